// Round 1
// baseline (209.580 us; speedup 1.0000x reference)
//
#include <hip/hip_runtime.h>

// YOLO v1 loss, faithful to the (buggy-inter) reference.
// pred/target: (N, 7, 7, 30) fp32 contiguous; per-cell 30 floats.
// Kernel 1: 256 cells/block, LDS-staged coalesced float4 loads, per-cell loss,
//           block reduction -> partial[blockIdx].
// Kernel 2: single block reduces partials, writes out[0] = sum / N_BATCH.

#define CH 30
#define CELLS_PER_BLOCK 256
#define BLOCK_THREADS 256
#define FLOATS_PER_BLOCK (CELLS_PER_BLOCK * CH)   // 7680
#define VEC4_PER_BLOCK (FLOATS_PER_BLOCK / 4)     // 1920
#define N_BATCH_F 16384.0f

__global__ __launch_bounds__(BLOCK_THREADS)
void yolo_partial(const float* __restrict__ pred,
                  const float* __restrict__ targ,
                  float* __restrict__ partial,
                  int n_cells) {
    __shared__ float sp[FLOATS_PER_BLOCK];
    __shared__ float st[FLOATS_PER_BLOCK];
    __shared__ float wave_sums[BLOCK_THREADS / 64];

    const int tid = threadIdx.x;
    const int cell0 = blockIdx.x * CELLS_PER_BLOCK;
    const int ncell_here = min(CELLS_PER_BLOCK, n_cells - cell0);
    const long long fbase = (long long)cell0 * CH;

    if (ncell_here == CELLS_PER_BLOCK) {
        // fast path: fully aligned float4 coalesced staging
        const float4* gp = (const float4*)(pred + fbase);
        const float4* gt = (const float4*)(targ + fbase);
        float4* lp = (float4*)sp;
        float4* lt4 = (float4*)st;
        for (int v = tid; v < VEC4_PER_BLOCK; v += BLOCK_THREADS) {
            lp[v] = gp[v];
            lt4[v] = gt[v];
        }
    } else {
        const int nflt = ncell_here * CH;
        for (int v = tid; v < nflt; v += BLOCK_THREADS) {
            sp[v] = pred[fbase + v];
            st[v] = targ[fbase + v];
        }
    }
    __syncthreads();

    float sum = 0.0f;
    if (tid < ncell_here) {
        const float* p = &sp[tid * CH];
        const float* t = &st[tid * CH];

        const float t4 = t[4];
        const float t9 = t[9];
        const float coo = (t4 > 0.0f) ? 1.0f : 0.0f;
        const float noo = 1.0f - coo;

        // no-object loss (weight 0.5)
        {
            const float d4 = p[4] - t4;
            const float d9 = p[9] - t9;
            sum += 0.5f * noo * (d4 * d4 + d9 * d9);
        }

        if (coo > 0.0f) {
            // class loss (channels 10..29), weight 1
            float cl = 0.0f;
#pragma unroll
            for (int c = 10; c < 30; ++c) {
                const float d = p[c] - t[c];
                cl += d * d;
            }
            sum += cl;

            // IoU of each pred box vs target box 0 (reference's exact math,
            // including the inverted "inter" indicator).
            const float t0x = t[0], t0y = t[1], t0w = t[2], t0h = t[3];
            const float tltx = t0x - 0.5f * t0w;
            const float tlty = t0y - 0.5f * t0h;
            const float trbx = t0x + 0.5f * t0w;
            const float trby = t0y + 0.5f * t0h;
            const float area2 = (trbx - tltx) * (trby - tlty);

            float iou0, iou1;
#pragma unroll
            for (int b = 0; b < 2; ++b) {
                const float* pb = p + b * 5;
                const float pltx = pb[0] - 0.5f * pb[2];
                const float plty = pb[1] - 0.5f * pb[3];
                const float prbx = pb[0] + 0.5f * pb[2];
                const float prby = pb[1] + 0.5f * pb[3];
                const float ltx = fmaxf(pltx, tltx);
                const float lty = fmaxf(plty, tlty);
                const float rbx = fminf(prbx, trbx);
                const float rby = fminf(prby, trby);
                const float wind = (rbx - ltx < 0.0f) ? 1.0f : 0.0f;
                const float hind = (rby - lty < 0.0f) ? 1.0f : 0.0f;
                const float inter = wind * hind;
                const float area1 = (prbx - pltx) * (prby - plty);
                const float iou = inter / (area1 + area2 - inter);
                if (b == 0) iou0 = iou; else iou1 = iou;
            }
            // jnp.argmax: first index of max -> idx=1 only if strictly greater
            const int idx = (iou1 > iou0) ? 1 : 0;
            const float* rp = p + idx * 5;
            const float* rt = t + idx * 5;

            // contain loss, weight 1
            const float dc = rp[4] - rt[4];
            sum += dc * dc;

            // localization loss, weight 5
            const float dx = rp[0] - rt[0];
            const float dy = rp[1] - rt[1];
            const float dw = sqrtf(rp[2]) - sqrtf(rt[2]);
            const float dh = sqrtf(rp[3]) - sqrtf(rt[3]);
            sum += 5.0f * (dx * dx + dy * dy + dw * dw + dh * dh);
        }
    }

    // block reduction: wave shuffle then LDS
#pragma unroll
    for (int off = 32; off > 0; off >>= 1)
        sum += __shfl_down(sum, off, 64);
    const int wave = tid >> 6;
    const int lane = tid & 63;
    if (lane == 0) wave_sums[wave] = sum;
    __syncthreads();
    if (tid == 0) {
        float tot = 0.0f;
#pragma unroll
        for (int w = 0; w < BLOCK_THREADS / 64; ++w) tot += wave_sums[w];
        partial[blockIdx.x] = tot;
    }
}

__global__ __launch_bounds__(256)
void yolo_reduce(const float* __restrict__ partial, int n, float* __restrict__ out) {
    __shared__ float wave_sums[4];
    float s = 0.0f;
    for (int i = threadIdx.x; i < n; i += 256)
        s += partial[i];
#pragma unroll
    for (int off = 32; off > 0; off >>= 1)
        s += __shfl_down(s, off, 64);
    const int wave = threadIdx.x >> 6;
    const int lane = threadIdx.x & 63;
    if (lane == 0) wave_sums[wave] = s;
    __syncthreads();
    if (threadIdx.x == 0) {
        float tot = wave_sums[0] + wave_sums[1] + wave_sums[2] + wave_sums[3];
        out[0] = tot * (1.0f / N_BATCH_F);
    }
}

extern "C" void kernel_launch(void* const* d_in, const int* in_sizes, int n_in,
                              void* d_out, int out_size, void* d_ws, size_t ws_size,
                              hipStream_t stream) {
    const float* pred = (const float*)d_in[0];
    const float* targ = (const float*)d_in[1];
    float* out = (float*)d_out;
    float* partial = (float*)d_ws;

    const int n_cells = in_sizes[0] / CH;                       // 802816
    const int blocks = (n_cells + CELLS_PER_BLOCK - 1) / CELLS_PER_BLOCK;  // 3136

    yolo_partial<<<blocks, BLOCK_THREADS, 0, stream>>>(pred, targ, partial, n_cells);
    yolo_reduce<<<1, 256, 0, stream>>>(partial, blocks, out);
}

// Round 2
// 204.214 us; speedup vs baseline: 1.0263x; 1.0263x over previous
//
#include <hip/hip_runtime.h>

// YOLO v1 loss. pred/target: (16384, 7, 7, 30) fp32.
// R2: two-phase single-LDS-buffer (30 KB) + async global_load_lds staging.
//   phase 1: stage target tile -> LDS (direct-to-LDS, width 16)
//            each thread pulls its cell's 30 target floats into registers
//   phase 2: stage pred tile into the SAME LDS buffer, compute per-cell loss
// Halved LDS -> 4 blocks/CU (vs 2), async staging removes VGPR roundtrip.

#define CH 30
#define CPB 256                   // cells per block
#define T 256                     // threads per block
#define TILE_F (CPB * CH)         // 7680 floats = 30720 B
#define TILE_V4 (TILE_F / 4)      // 1920 float4

typedef __attribute__((address_space(3))) void* lds_vp;
typedef const __attribute__((address_space(1))) void* gvp;

__global__ __launch_bounds__(T, 4)
void yolo_partial(const float* __restrict__ pred,
                  const float* __restrict__ targ,
                  float* __restrict__ partial) {
    __shared__ float tile[TILE_F];
    __shared__ float wave_sums[T / 64];

    const int tid = threadIdx.x;
    const long long fbase = (long long)blockIdx.x * TILE_F;

    // ---- phase 1: stage TARGET tile, async direct-to-LDS ----
    {
        const float4* gt = (const float4*)(targ + fbase);
#pragma unroll
        for (int k = 0; k < 8; ++k) {
            const int v = tid + k * T;
            if (v < TILE_V4)
                __builtin_amdgcn_global_load_lds((gvp)(gt + v), (lds_vp)(tile + v * 4),
                                                 16, 0, 0);
        }
    }
    __syncthreads();   // drains vmcnt before barrier

    // pull this cell's 30 target floats into registers (float2 = 8B aligned)
    float2 t01, t23, t45, t67, t89, tc[10];
    {
        const float2* t2 = (const float2*)(tile + tid * CH);
        t01 = t2[0]; t23 = t2[1]; t45 = t2[2]; t67 = t2[3]; t89 = t2[4];
#pragma unroll
        for (int k = 0; k < 10; ++k) tc[k] = t2[5 + k];
    }
    __syncthreads();   // everyone done reading target before overwrite

    // ---- phase 2: stage PRED tile into the same LDS ----
    {
        const float4* gp = (const float4*)(pred + fbase);
#pragma unroll
        for (int k = 0; k < 8; ++k) {
            const int v = tid + k * T;
            if (v < TILE_V4)
                __builtin_amdgcn_global_load_lds((gvp)(gp + v), (lds_vp)(tile + v * 4),
                                                 16, 0, 0);
        }
    }
    __syncthreads();

    float sum = 0.0f;
    {
        const float2* p2 = (const float2*)(tile + tid * CH);
        const float2 p01 = p2[0], p23 = p2[1], p45 = p2[2], p67 = p2[3], p89 = p2[4];

        const float t4 = t45.x, t9 = t89.y;
        const bool coo = t4 > 0.0f;

        // no-object loss (weight 0.5)
        const float d4 = p45.x - t4;
        const float d9 = p89.y - t9;
        sum = coo ? 0.0f : 0.5f * (d4 * d4 + d9 * d9);

        if (coo) {
            // class loss (channels 10..29)
            float cl = 0.0f;
#pragma unroll
            for (int k = 0; k < 10; ++k) {
                const float2 pc = p2[5 + k];
                const float dx = pc.x - tc[k].x;
                const float dy = pc.y - tc[k].y;
                cl += dx * dx + dy * dy;
            }
            sum += cl;

            // target box 0 corners (reference's exact math incl. inverted inter)
            const float tltx = t01.x - 0.5f * t23.x;
            const float tlty = t01.y - 0.5f * t23.y;
            const float trbx = t01.x + 0.5f * t23.x;
            const float trby = t01.y + 0.5f * t23.y;
            const float area2 = (trbx - tltx) * (trby - tlty);

            // pred box 0: ch 0..4, pred box 1: ch 5..9
            const float b0x = p01.x, b0y = p01.y, b0w = p23.x, b0h = p23.y;
            const float b1x = p45.y, b1y = p67.x, b1w = p67.y, b1h = p89.x;

            float iou0, iou1;
            {
                const float pltx = b0x - 0.5f * b0w, plty = b0y - 0.5f * b0h;
                const float prbx = b0x + 0.5f * b0w, prby = b0y + 0.5f * b0h;
                const float ltx = fmaxf(pltx, tltx), lty = fmaxf(plty, tlty);
                const float rbx = fminf(prbx, trbx), rby = fminf(prby, trby);
                const float inter = ((rbx - ltx < 0.0f) ? 1.0f : 0.0f) *
                                    ((rby - lty < 0.0f) ? 1.0f : 0.0f);
                const float area1 = (prbx - pltx) * (prby - plty);
                iou0 = inter / (area1 + area2 - inter);
            }
            {
                const float pltx = b1x - 0.5f * b1w, plty = b1y - 0.5f * b1h;
                const float prbx = b1x + 0.5f * b1w, prby = b1y + 0.5f * b1h;
                const float ltx = fmaxf(pltx, tltx), lty = fmaxf(plty, tlty);
                const float rbx = fminf(prbx, trbx), rby = fminf(prby, trby);
                const float inter = ((rbx - ltx < 0.0f) ? 1.0f : 0.0f) *
                                    ((rby - lty < 0.0f) ? 1.0f : 0.0f);
                const float area1 = (prbx - pltx) * (prby - plty);
                iou1 = inter / (area1 + area2 - inter);
            }
            // jnp.argmax first-index tie-break: idx=1 only if strictly greater
            const bool idx1 = iou1 > iou0;

            // responsible pred box (static selects, no dynamic reg indexing)
            const float rpx = idx1 ? b1x : b0x;
            const float rpy = idx1 ? b1y : b0y;
            const float rpw = idx1 ? b1w : b0w;
            const float rph = idx1 ? b1h : b0h;
            const float rpc = idx1 ? p89.y : p45.x;
            // responsible target box
            const float rtx = idx1 ? t45.y : t01.x;
            const float rty = idx1 ? t67.x : t01.y;
            const float rtw = idx1 ? t67.y : t23.x;
            const float rth = idx1 ? t89.x : t23.y;
            const float rtc = idx1 ? t89.y : t45.x;

            // contain loss (weight 1)
            const float dc = rpc - rtc;
            sum += dc * dc;

            // localization loss (weight 5)
            const float dx = rpx - rtx;
            const float dy = rpy - rty;
            const float dw = sqrtf(rpw) - sqrtf(rtw);
            const float dh = sqrtf(rph) - sqrtf(rth);
            sum += 5.0f * (dx * dx + dy * dy + dw * dw + dh * dh);
        }
    }

    // block reduction: wave shuffle then LDS
#pragma unroll
    for (int off = 32; off > 0; off >>= 1)
        sum += __shfl_down(sum, off, 64);
    const int wave = tid >> 6;
    const int lane = tid & 63;
    if (lane == 0) wave_sums[wave] = sum;
    __syncthreads();
    if (tid == 0) {
        float tot = 0.0f;
#pragma unroll
        for (int w = 0; w < T / 64; ++w) tot += wave_sums[w];
        partial[blockIdx.x] = tot;
    }
}

__global__ __launch_bounds__(256)
void yolo_reduce(const float* __restrict__ partial, int n, float* __restrict__ out) {
    __shared__ float wave_sums[4];
    float s = 0.0f;
    const int n4 = n >> 2;
    const float4* p4 = (const float4*)partial;
    for (int v = threadIdx.x; v < n4; v += 256) {
        const float4 x = p4[v];
        s += (x.x + x.y) + (x.z + x.w);
    }
    // tail (n not multiple of 4)
    for (int v = (n4 << 2) + threadIdx.x; v < n; v += 256)
        s += partial[v];
#pragma unroll
    for (int off = 32; off > 0; off >>= 1)
        s += __shfl_down(s, off, 64);
    const int wave = threadIdx.x >> 6;
    const int lane = threadIdx.x & 63;
    if (lane == 0) wave_sums[wave] = s;
    __syncthreads();
    if (threadIdx.x == 0) {
        const float tot = wave_sums[0] + wave_sums[1] + wave_sums[2] + wave_sums[3];
        out[0] = tot * (1.0f / 16384.0f);
    }
}

extern "C" void kernel_launch(void* const* d_in, const int* in_sizes, int n_in,
                              void* d_out, int out_size, void* d_ws, size_t ws_size,
                              hipStream_t stream) {
    const float* pred = (const float*)d_in[0];
    const float* targ = (const float*)d_in[1];
    float* out = (float*)d_out;
    float* partial = (float*)d_ws;

    const int n_cells = in_sizes[0] / CH;              // 802816 (divisible by 256)
    const int blocks = n_cells / CPB;                  // 3136

    yolo_partial<<<blocks, T, 0, stream>>>(pred, targ, partial);
    yolo_reduce<<<1, 256, 0, stream>>>(partial, blocks, out);
}